// Round 4
// baseline (356.084 us; speedup 1.0000x reference)
//
#include <hip/hip_runtime.h>

#define S_DIM 4
#define A_DIM 64
#define B_DIM 2048
#define D_DIM 384
#define H1D 128
#define H2D 128
#define H3D 64
#define MT 64   // batch rows per block
#define XROW (A_DIM * D_DIM)   // x row stride in floats

typedef __attribute__((ext_vector_type(8))) short short8;
typedef __attribute__((ext_vector_type(4))) float float4v;

__device__ __forceinline__ unsigned short f2bf(float f) {
  unsigned u = __float_as_uint(f);
  u += 0x7FFFu + ((u >> 16) & 1u);   // round-to-nearest-even
  return (unsigned short)(u >> 16);
}

// LDS-tiled transpose + bf16 convert: coalesced reads AND writes.
// out layouts (N-major): W0T[s][h1][d], W1T[s][h2][h1], W2T[s][h3][h2]
__global__ __launch_bounds__(256) void prep_weights(
    const float* __restrict__ W0, const float* __restrict__ W1,
    const float* __restrict__ W2,
    unsigned short* __restrict__ W0T, unsigned short* __restrict__ W1T,
    unsigned short* __restrict__ W2T) {
  __shared__ float tile[32][33];
  int b = blockIdx.x;
  const float* src; unsigned short* dst; int R, C, dt, ht, s;
  if (b < 192) {                 // W0: 4 x 12 x 4 tiles
    s = b / 48; int t = b % 48; dt = t / 4; ht = t % 4;
    src = W0 + s * D_DIM * H1D; dst = W0T + s * H1D * D_DIM; R = D_DIM; C = H1D;
  } else if (b < 256) {          // W1: 4 x 4 x 4
    int bb = b - 192; s = bb / 16; int t = bb % 16; dt = t / 4; ht = t % 4;
    src = W1 + s * H1D * H2D; dst = W1T + s * H2D * H1D; R = H1D; C = H2D;
  } else {                       // W2: 4 x 4 x 2
    int bb = b - 256; s = bb / 8; int t = bb % 8; dt = t / 2; ht = t % 2;
    src = W2 + s * H2D * H3D; dst = W2T + s * H3D * H2D; R = H2D; C = H3D;
  }
  int tx = threadIdx.x & 31, ty = threadIdx.x >> 5;
#pragma unroll
  for (int k = 0; k < 4; ++k)
    tile[ty + 8 * k][tx] = src[(size_t)(dt * 32 + ty + 8 * k) * C + ht * 32 + tx];
  __syncthreads();
#pragma unroll
  for (int k = 0; k < 4; ++k)
    dst[(size_t)(ht * 32 + ty + 8 * k) * R + dt * 32 + tx] = f2bf(tile[tx][ty + 8 * k]);
}

// Block = 1 atom x 64 batch rows. L0 streams x A-frags DIRECTLY from global
// (L2-hot within block, no staging barriers); weights live in registers.
// LDS only holds activations; 3 barriers total.
__global__ __launch_bounds__(256, 4) void mlp_fused(
    const float* __restrict__ x, const int* __restrict__ species,
    const unsigned short* __restrict__ W0T, const unsigned short* __restrict__ W1T,
    const unsigned short* __restrict__ W2T,
    const float* __restrict__ b0, const float* __restrict__ b1,
    const float* __restrict__ b2, const float* __restrict__ W3,
    const float* __restrict__ b3, float* __restrict__ out) {
  // 136-short row stride: 16B-aligned b128 reads, <=2-way bank aliasing (free).
  __shared__ __align__(16) unsigned short H0[MT * 136];
  __shared__ __align__(16) unsigned short H1[MT * 136];
  __shared__ float W3s[H3D];
  float* H2 = (float*)H0;   // [64][68] fp32, aliases H0 (dead after L1's barrier)

  const int a = blockIdx.y;
  const int brow0 = blockIdx.x * MT;
  const int sp = species[a];
  const int tid = threadIdx.x;
  const int wave = tid >> 6;
  const int lane = tid & 63;
  const int q = lane >> 4;   // A/B k-quad, C/D row-quad
  const int r = lane & 15;   // A row / B col / C col

  if (tid < H3D) W3s[tid] = W3[sp * H3D + tid];

  const float4v zero = {0.f, 0.f, 0.f, 0.f};

  // ---------------- layer 0: [64x384] @ [384x128], pure streaming, no barriers ------
  float4v acc0[4][2];
#pragma unroll
  for (int g = 0; g < 4; ++g) { acc0[g][0] = zero; acc0[g][1] = zero; }

  // lane's A-source: row (brow0 + g*16 + r) of x at atom a, k-offset q*8
  const float* xb = x + ((size_t)brow0 * A_DIM + a) * D_DIM + (size_t)r * XROW + q * 8;
  const unsigned short* w0base =
      W0T + (size_t)sp * H1D * D_DIM + (wave * 32 + r) * D_DIM + q * 8;

#pragma unroll 1
  for (int st = 0; st < 3; ++st) {
    const int ks = st * 128;
#pragma unroll
    for (int kk = 0; kk < 4; ++kk) {
      short8 bn0 = *(const short8*)(w0base + ks + kk * 32);
      short8 bn1 = *(const short8*)(w0base + 16 * D_DIM + ks + kk * 32);
#pragma unroll
      for (int g = 0; g < 4; ++g) {
        const float* ap = xb + (size_t)g * 16 * XROW + ks + kk * 32;
        float4v a0 = *(const float4v*)ap;
        float4v a1 = *(const float4v*)(ap + 4);
        short8 af;
        af[0] = (short)f2bf(a0[0]); af[1] = (short)f2bf(a0[1]);
        af[2] = (short)f2bf(a0[2]); af[3] = (short)f2bf(a0[3]);
        af[4] = (short)f2bf(a1[0]); af[5] = (short)f2bf(a1[1]);
        af[6] = (short)f2bf(a1[2]); af[7] = (short)f2bf(a1[3]);
        acc0[g][0] = __builtin_amdgcn_mfma_f32_16x16x32_bf16(af, bn0, acc0[g][0], 0, 0, 0);
        acc0[g][1] = __builtin_amdgcn_mfma_f32_16x16x32_bf16(af, bn1, acc0[g][1], 0, 0, 0);
      }
    }
  }
  {
    const float* b0p = b0 + sp * H1D;
#pragma unroll
    for (int n = 0; n < 2; ++n) {
      float bias = b0p[wave * 32 + n * 16 + r];
#pragma unroll
      for (int g = 0; g < 4; ++g)
#pragma unroll
        for (int i = 0; i < 4; ++i) {
          float y = acc0[g][n][i] + bias;
          H0[(g * 16 + q * 4 + i) * 136 + wave * 32 + n * 16 + r] = f2bf(__expf(-y * y));
        }
    }
  }
  __syncthreads();   // (1) H0 complete

  // ---------------- layer 1: [64x128] @ [128x128]; H0 -> H1 ----------------
  {
    float4v acc1[4][2];
#pragma unroll
    for (int g = 0; g < 4; ++g) { acc1[g][0] = zero; acc1[g][1] = zero; }
    const unsigned short* w1base =
        W1T + (size_t)sp * H2D * H1D + (wave * 32 + r) * H1D + q * 8;
    short8 bf[4][2];
#pragma unroll
    for (int kk = 0; kk < 4; ++kk)
#pragma unroll
      for (int n = 0; n < 2; ++n)
        bf[kk][n] = *(const short8*)(w1base + n * 16 * H1D + kk * 32);
#pragma unroll
    for (int g = 0; g < 4; ++g)
#pragma unroll
      for (int kk = 0; kk < 4; ++kk) {
        short8 af = *(const short8*)(H0 + (g * 16 + r) * 136 + kk * 32 + q * 8);
        acc1[g][0] = __builtin_amdgcn_mfma_f32_16x16x32_bf16(af, bf[kk][0], acc1[g][0], 0, 0, 0);
        acc1[g][1] = __builtin_amdgcn_mfma_f32_16x16x32_bf16(af, bf[kk][1], acc1[g][1], 0, 0, 0);
      }
    const float* b1p = b1 + sp * H2D;
#pragma unroll
    for (int n = 0; n < 2; ++n) {
      float bias = b1p[wave * 32 + n * 16 + r];
#pragma unroll
      for (int g = 0; g < 4; ++g)
#pragma unroll
        for (int i = 0; i < 4; ++i) {
          float y = acc1[g][n][i] + bias;
          H1[(g * 16 + q * 4 + i) * 136 + wave * 32 + n * 16 + r] = f2bf(__expf(-y * y));
        }
    }
  }
  __syncthreads();   // (2) H1 complete; all H0 reads done (H2 may overwrite H0)

  // ---------------- layer 2: [64x128] @ [128x64]; H1 -> H2 ----------------
  {
    float4v acc2[4];
#pragma unroll
    for (int g = 0; g < 4; ++g) acc2[g] = zero;
    const unsigned short* w2base =
        W2T + (size_t)sp * H3D * H2D + (wave * 16 + r) * H2D + q * 8;
    short8 bf[4];
#pragma unroll
    for (int kk = 0; kk < 4; ++kk)
      bf[kk] = *(const short8*)(w2base + kk * 32);
#pragma unroll
    for (int g = 0; g < 4; ++g)
#pragma unroll
      for (int kk = 0; kk < 4; ++kk) {
        short8 af = *(const short8*)(H1 + (g * 16 + r) * 136 + kk * 32 + q * 8);
        acc2[g] = __builtin_amdgcn_mfma_f32_16x16x32_bf16(af, bf[kk], acc2[g], 0, 0, 0);
      }
    float bias = b2[sp * H3D + wave * 16 + r];
#pragma unroll
    for (int g = 0; g < 4; ++g)
#pragma unroll
      for (int i = 0; i < 4; ++i) {
        float y = acc2[g][i] + bias;
        H2[(g * 16 + q * 4 + i) * 68 + wave * 16 + r] = __expf(-y * y);
      }
  }
  __syncthreads();   // (3) H2 complete

  // ---------------- layer 3: dot with W3[64] + cross-atom atomic sum ----------------
  {
    const int row = tid >> 2;
    const int seg = tid & 3;
    const float4v* h2p = (const float4v*)(H2 + row * 68 + seg * 16);
    const float4v* w3p = (const float4v*)(W3s + seg * 16);
    float4v sv = zero;
#pragma unroll
    for (int jj = 0; jj < 4; ++jj) sv += h2p[jj] * w3p[jj];
    float s = sv[0] + sv[1] + sv[2] + sv[3];
    s += __shfl_xor(s, 1);
    s += __shfl_xor(s, 2);
    if (seg == 0) atomicAdd(&out[brow0 + row], s + b3[sp]);
  }
}

extern "C" void kernel_launch(void* const* d_in, const int* in_sizes, int n_in,
                              void* d_out, int out_size, void* d_ws, size_t ws_size,
                              hipStream_t stream) {
  const float* x       = (const float*)d_in[0];
  const int*   species = (const int*)d_in[1];
  const float* W0 = (const float*)d_in[2];
  const float* b0 = (const float*)d_in[3];
  const float* W1 = (const float*)d_in[4];
  const float* b1 = (const float*)d_in[5];
  const float* W2 = (const float*)d_in[6];
  const float* b2 = (const float*)d_in[7];
  const float* W3 = (const float*)d_in[8];
  const float* b3 = (const float*)d_in[9];
  float* out = (float*)d_out;

  unsigned short* W0T = (unsigned short*)d_ws;
  unsigned short* W1T = W0T + S_DIM * H1D * D_DIM;
  unsigned short* W2T = W1T + S_DIM * H2D * H1D;

  hipMemsetAsync(d_out, 0, out_size * sizeof(float), stream);
  prep_weights<<<dim3(288), dim3(256), 0, stream>>>(W0, W1, W2, W0T, W1T, W2T);
  mlp_fused<<<dim3(B_DIM / MT, A_DIM), dim3(256), 0, stream>>>(
      x, species, W0T, W1T, W2T, b0, b1, b2, W3, b3, out);
}

// Round 5
// 310.289 us; speedup vs baseline: 1.1476x; 1.1476x over previous
//
#include <hip/hip_runtime.h>

#define S_DIM 4
#define A_DIM 64
#define B_DIM 2048
#define D_DIM 384
#define H1D 128
#define H2D 128
#define H3D 64
#define MT 64   // batch rows per block

typedef __attribute__((ext_vector_type(8))) short short8;
typedef __attribute__((ext_vector_type(4))) float float4v;

__device__ __forceinline__ unsigned short f2bf(float f) {
  unsigned u = __float_as_uint(f);
  u += 0x7FFFu + ((u >> 16) & 1u);   // round-to-nearest-even
  return (unsigned short)(u >> 16);
}

__device__ __forceinline__ void store_bf4(unsigned short* p, float4v v) {
  union { unsigned short s[4]; uint2 u; } t;
  t.s[0] = f2bf(v[0]); t.s[1] = f2bf(v[1]);
  t.s[2] = f2bf(v[2]); t.s[3] = f2bf(v[3]);
  *(uint2*)p = t.u;   // one ds_write_b64
}

// LDS-tiled transpose + bf16 convert: coalesced reads AND writes.
// out layouts (N-major): W0T[s][h1][d], W1T[s][h2][h1], W2T[s][h3][h2]
__global__ __launch_bounds__(256) void prep_weights(
    const float* __restrict__ W0, const float* __restrict__ W1,
    const float* __restrict__ W2,
    unsigned short* __restrict__ W0T, unsigned short* __restrict__ W1T,
    unsigned short* __restrict__ W2T) {
  __shared__ float tile[32][33];
  int b = blockIdx.x;
  const float* src; unsigned short* dst; int R, C, dt, ht, s;
  if (b < 192) {                 // W0: 4 x 12 x 4 tiles
    s = b / 48; int t = b % 48; dt = t / 4; ht = t % 4;
    src = W0 + s * D_DIM * H1D; dst = W0T + s * H1D * D_DIM; R = D_DIM; C = H1D;
  } else if (b < 256) {          // W1: 4 x 4 x 4
    int bb = b - 192; s = bb / 16; int t = bb % 16; dt = t / 4; ht = t % 4;
    src = W1 + s * H1D * H2D; dst = W1T + s * H2D * H1D; R = H1D; C = H2D;
  } else {                       // W2: 4 x 4 x 2
    int bb = b - 256; s = bb / 8; int t = bb % 8; dt = t / 2; ht = t % 2;
    src = W2 + s * H2D * H3D; dst = W2T + s * H3D * H2D; R = H2D; C = H3D;
  }
  int tx = threadIdx.x & 31, ty = threadIdx.x >> 5;
#pragma unroll
  for (int k = 0; k < 4; ++k)
    tile[ty + 8 * k][tx] = src[(size_t)(dt * 32 + ty + 8 * k) * C + ht * 32 + tx];
  __syncthreads();
#pragma unroll
  for (int k = 0; k < 4; ++k)
    dst[(size_t)(ht * 32 + ty + 8 * k) * R + dt * 32 + tx] = f2bf(tile[tx][ty + 8 * k]);
}

// Block = 1 atom x 64 rows. L0: double-buffered 128-k x chunks, next chunk's
// global loads in flight across the current chunk's MFMA burst (fine vmcnt).
// H0/H1/H2 alias the x buffers -> 35 KB LDS -> 4 blocks/CU. 6 barriers.
__global__ __launch_bounds__(256, 4) void mlp_fused(
    const float* __restrict__ x, const int* __restrict__ species,
    const unsigned short* __restrict__ W0T, const unsigned short* __restrict__ W1T,
    const unsigned short* __restrict__ W2T,
    const float* __restrict__ b0, const float* __restrict__ b1,
    const float* __restrict__ b2, const float* __restrict__ W3,
    const float* __restrict__ b3, float* __restrict__ out) {
  // 136-short row stride: 16B-aligned b128 reads, <=2-way bank aliasing (free).
  __shared__ __align__(16) unsigned short xbuf0[MT * 136];  // c0,c2; later H1
  __shared__ __align__(16) unsigned short xbuf1[MT * 136];  // c1;    later H0, then H2
  __shared__ float W3s[H3D];
  unsigned short* H0 = xbuf1;
  unsigned short* H1 = xbuf0;
  float* H2 = (float*)xbuf1;   // [64][68] fp32

  const int a = blockIdx.y;
  const int brow0 = blockIdx.x * MT;
  const int sp = species[a];
  const int tid = threadIdx.x;
  const int wave = tid >> 6;
  const int lane = tid & 63;
  const int q = lane >> 4;   // A/B k-quad, C/D row-quad
  const int r = lane & 15;   // A row / B col / C col

  const float4v zero = {0.f, 0.f, 0.f, 0.f};

  // staging coords: thread covers row tid>>2, 16B piece (tid&3), 64B stride
  const int srow = tid >> 2;
  const int c4 = tid & 3;
  const float* xrow = x + ((size_t)(brow0 + srow) * A_DIM + a) * D_DIM + c4 * 4;
  const unsigned short* w0base =
      W0T + (size_t)sp * H1D * D_DIM + (wave * 32 + r) * D_DIM + q * 8;

  // ---- prologue: chunk 0 loads -> convert -> xbuf0 ----
  float4v xv[8];
#pragma unroll
  for (int j = 0; j < 8; ++j) xv[j] = *(const float4v*)(xrow + j * 16);
  if (tid < H3D) W3s[tid] = W3[sp * H3D + tid];
  short8 bf[4][2];
#pragma unroll
  for (int kk = 0; kk < 4; ++kk)
#pragma unroll
    for (int n = 0; n < 2; ++n)
      bf[kk][n] = *(const short8*)(w0base + n * 16 * D_DIM + kk * 32);
  {
    unsigned short* xd = xbuf0 + srow * 136 + c4 * 4;
#pragma unroll
    for (int j = 0; j < 8; ++j) store_bf4(xd + j * 16, xv[j]);
  }
  __syncthreads();   // (b0) xbuf0 published

  float4v acc0[4][2];
#pragma unroll
  for (int g = 0; g < 4; ++g) { acc0[g][0] = zero; acc0[g][1] = zero; }

  // ---- chunk 0: MFMA on xbuf0; chunk-1 x loads in flight ----
#pragma unroll
  for (int j = 0; j < 8; ++j) xv[j] = *(const float4v*)(xrow + 128 + j * 16);
#pragma unroll
  for (int g = 0; g < 4; ++g)
#pragma unroll
    for (int kk = 0; kk < 4; ++kk) {
      short8 af = *(const short8*)(xbuf0 + (g * 16 + r) * 136 + kk * 32 + q * 8);
      acc0[g][0] = __builtin_amdgcn_mfma_f32_16x16x32_bf16(af, bf[kk][0], acc0[g][0], 0, 0, 0);
      acc0[g][1] = __builtin_amdgcn_mfma_f32_16x16x32_bf16(af, bf[kk][1], acc0[g][1], 0, 0, 0);
    }
  {
    unsigned short* xd = xbuf1 + srow * 136 + c4 * 4;
#pragma unroll
    for (int j = 0; j < 8; ++j) store_bf4(xd + j * 16, xv[j]);
  }
  __syncthreads();   // (b1) xbuf1 published

  // ---- chunk 1: bf(c1) first, then chunk-2 x loads, MFMA waits only on bf ----
#pragma unroll
  for (int kk = 0; kk < 4; ++kk)
#pragma unroll
    for (int n = 0; n < 2; ++n)
      bf[kk][n] = *(const short8*)(w0base + n * 16 * D_DIM + 128 + kk * 32);
#pragma unroll
  for (int j = 0; j < 8; ++j) xv[j] = *(const float4v*)(xrow + 256 + j * 16);
#pragma unroll
  for (int g = 0; g < 4; ++g)
#pragma unroll
    for (int kk = 0; kk < 4; ++kk) {
      short8 af = *(const short8*)(xbuf1 + (g * 16 + r) * 136 + kk * 32 + q * 8);
      acc0[g][0] = __builtin_amdgcn_mfma_f32_16x16x32_bf16(af, bf[kk][0], acc0[g][0], 0, 0, 0);
      acc0[g][1] = __builtin_amdgcn_mfma_f32_16x16x32_bf16(af, bf[kk][1], acc0[g][1], 0, 0, 0);
    }
  {
    unsigned short* xd = xbuf0 + srow * 136 + c4 * 4;
#pragma unroll
    for (int j = 0; j < 8; ++j) store_bf4(xd + j * 16, xv[j]);
  }
  __syncthreads();   // (b2) xbuf0 re-published (chunk 2)

  // ---- chunk 2: MFMA on xbuf0 ----
#pragma unroll
  for (int kk = 0; kk < 4; ++kk)
#pragma unroll
    for (int n = 0; n < 2; ++n)
      bf[kk][n] = *(const short8*)(w0base + n * 16 * D_DIM + 256 + kk * 32);
#pragma unroll
  for (int g = 0; g < 4; ++g)
#pragma unroll
    for (int kk = 0; kk < 4; ++kk) {
      short8 af = *(const short8*)(xbuf0 + (g * 16 + r) * 136 + kk * 32 + q * 8);
      acc0[g][0] = __builtin_amdgcn_mfma_f32_16x16x32_bf16(af, bf[kk][0], acc0[g][0], 0, 0, 0);
      acc0[g][1] = __builtin_amdgcn_mfma_f32_16x16x32_bf16(af, bf[kk][1], acc0[g][1], 0, 0, 0);
    }
  // H0 (=xbuf1) writes: xbuf1's last reads drained at barrier (b2); other
  // waves' chunk-2 MFMA touches only xbuf0 -> no barrier needed here.
  {
    const float* b0p = b0 + sp * H1D;
#pragma unroll
    for (int n = 0; n < 2; ++n) {
      float bias = b0p[wave * 32 + n * 16 + r];
#pragma unroll
      for (int g = 0; g < 4; ++g)
#pragma unroll
        for (int i = 0; i < 4; ++i) {
          float y = acc0[g][n][i] + bias;
          H0[(g * 16 + q * 4 + i) * 136 + wave * 32 + n * 16 + r] = f2bf(__expf(-y * y));
        }
    }
  }
  __syncthreads();   // (b3) H0 published; everyone past chunk-2 MFMA (xbuf0 free)

  // ---------------- layer 1: [64x128] @ [128x128]; H0 -> H1 (=xbuf0) ----------------
  {
    float4v acc1[4][2];
#pragma unroll
    for (int g = 0; g < 4; ++g) { acc1[g][0] = zero; acc1[g][1] = zero; }
    const unsigned short* w1base =
        W1T + (size_t)sp * H2D * H1D + (wave * 32 + r) * H1D + q * 8;
    short8 wf[4][2];
#pragma unroll
    for (int kk = 0; kk < 4; ++kk)
#pragma unroll
      for (int n = 0; n < 2; ++n)
        wf[kk][n] = *(const short8*)(w1base + n * 16 * H1D + kk * 32);
#pragma unroll
    for (int g = 0; g < 4; ++g)
#pragma unroll
      for (int kk = 0; kk < 4; ++kk) {
        short8 af = *(const short8*)(H0 + (g * 16 + r) * 136 + kk * 32 + q * 8);
        acc1[g][0] = __builtin_amdgcn_mfma_f32_16x16x32_bf16(af, wf[kk][0], acc1[g][0], 0, 0, 0);
        acc1[g][1] = __builtin_amdgcn_mfma_f32_16x16x32_bf16(af, wf[kk][1], acc1[g][1], 0, 0, 0);
      }
    const float* b1p = b1 + sp * H2D;
#pragma unroll
    for (int n = 0; n < 2; ++n) {
      float bias = b1p[wave * 32 + n * 16 + r];
#pragma unroll
      for (int g = 0; g < 4; ++g)
#pragma unroll
        for (int i = 0; i < 4; ++i) {
          float y = acc1[g][n][i] + bias;
          H1[(g * 16 + q * 4 + i) * 136 + wave * 32 + n * 16 + r] = f2bf(__expf(-y * y));
        }
    }
  }
  __syncthreads();   // (b4) H1 published; all H0 reads done

  // ---------------- layer 2: [64x128] @ [128x64]; H1 -> H2 (=xbuf1) ----------------
  {
    float4v acc2[4];
#pragma unroll
    for (int g = 0; g < 4; ++g) acc2[g] = zero;
    const unsigned short* w2base =
        W2T + (size_t)sp * H3D * H2D + (wave * 16 + r) * H2D + q * 8;
    short8 wf[4];
#pragma unroll
    for (int kk = 0; kk < 4; ++kk)
      wf[kk] = *(const short8*)(w2base + kk * 32);
#pragma unroll
    for (int g = 0; g < 4; ++g)
#pragma unroll
      for (int kk = 0; kk < 4; ++kk) {
        short8 af = *(const short8*)(H1 + (g * 16 + r) * 136 + kk * 32 + q * 8);
        acc2[g] = __builtin_amdgcn_mfma_f32_16x16x32_bf16(af, wf[kk], acc2[g], 0, 0, 0);
      }
    float bias = b2[sp * H3D + wave * 16 + r];
#pragma unroll
    for (int g = 0; g < 4; ++g)
#pragma unroll
      for (int i = 0; i < 4; ++i) {
        float y = acc2[g][i] + bias;
        H2[(g * 16 + q * 4 + i) * 68 + wave * 16 + r] = __expf(-y * y);
      }
  }
  __syncthreads();   // (b5) H2 published

  // ---------------- layer 3: dot with W3[64] + cross-atom atomic sum ----------------
  {
    const int row = tid >> 2;
    const int seg = tid & 3;
    const float4v* h2p = (const float4v*)(H2 + row * 68 + seg * 16);
    const float4v* w3p = (const float4v*)(W3s + seg * 16);
    float4v sv = zero;
#pragma unroll
    for (int jj = 0; jj < 4; ++jj) sv += h2p[jj] * w3p[jj];
    float s = sv[0] + sv[1] + sv[2] + sv[3];
    s += __shfl_xor(s, 1);
    s += __shfl_xor(s, 2);
    if (seg == 0) atomicAdd(&out[brow0 + row], s + b3[sp]);
  }
}

extern "C" void kernel_launch(void* const* d_in, const int* in_sizes, int n_in,
                              void* d_out, int out_size, void* d_ws, size_t ws_size,
                              hipStream_t stream) {
  const float* x       = (const float*)d_in[0];
  const int*   species = (const int*)d_in[1];
  const float* W0 = (const float*)d_in[2];
  const float* b0 = (const float*)d_in[3];
  const float* W1 = (const float*)d_in[4];
  const float* b1 = (const float*)d_in[5];
  const float* W2 = (const float*)d_in[6];
  const float* b2 = (const float*)d_in[7];
  const float* W3 = (const float*)d_in[8];
  const float* b3 = (const float*)d_in[9];
  float* out = (float*)d_out;

  unsigned short* W0T = (unsigned short*)d_ws;
  unsigned short* W1T = W0T + S_DIM * H1D * D_DIM;
  unsigned short* W2T = W1T + S_DIM * H2D * H1D;

  hipMemsetAsync(d_out, 0, out_size * sizeof(float), stream);
  prep_weights<<<dim3(288), dim3(256), 0, stream>>>(W0, W1, W2, W0T, W1T, W2T);
  mlp_fused<<<dim3(B_DIM / MT, A_DIM), dim3(256), 0, stream>>>(
      x, species, W0T, W1T, W2T, b0, b1, b2, W3, b3, out);
}

// Round 6
// 305.218 us; speedup vs baseline: 1.1667x; 1.0166x over previous
//
#include <hip/hip_runtime.h>

#define S_DIM 4
#define A_DIM 64
#define B_DIM 2048
#define D_DIM 384
#define H1D 128
#define H2D 128
#define H3D 64
#define MT 64   // batch rows per block
#define XROW (A_DIM * D_DIM)   // x row stride in floats (98304 B)

typedef __attribute__((ext_vector_type(8))) short short8;
typedef __attribute__((ext_vector_type(4))) float float4v;

__device__ __forceinline__ unsigned short f2bf(float f) {
  unsigned u = __float_as_uint(f);
  u += 0x7FFFu + ((u >> 16) & 1u);   // round-to-nearest-even
  return (unsigned short)(u >> 16);
}

__device__ __forceinline__ void store_bf4(unsigned short* p, float4v v) {
  union { unsigned short s[4]; uint2 u; } t;
  t.s[0] = f2bf(v[0]); t.s[1] = f2bf(v[1]);
  t.s[2] = f2bf(v[2]); t.s[3] = f2bf(v[3]);
  *(uint2*)p = t.u;   // one ds_write_b64
}

// LDS-tiled transpose + bf16 convert: coalesced reads AND writes.
// out layouts (N-major): W0T[s][h1][d], W1T[s][h2][h1], W2T[s][h3][h2]
__global__ __launch_bounds__(256) void prep_weights(
    const float* __restrict__ W0, const float* __restrict__ W1,
    const float* __restrict__ W2,
    unsigned short* __restrict__ W0T, unsigned short* __restrict__ W1T,
    unsigned short* __restrict__ W2T) {
  __shared__ float tile[32][33];
  int b = blockIdx.x;
  const float* src; unsigned short* dst; int R, C, dt, ht, s;
  if (b < 192) {                 // W0: 4 x 12 x 4 tiles
    s = b / 48; int t = b % 48; dt = t / 4; ht = t % 4;
    src = W0 + s * D_DIM * H1D; dst = W0T + s * H1D * D_DIM; R = D_DIM; C = H1D;
  } else if (b < 256) {          // W1: 4 x 4 x 4
    int bb = b - 192; s = bb / 16; int t = bb % 16; dt = t / 4; ht = t % 4;
    src = W1 + s * H1D * H2D; dst = W1T + s * H2D * H1D; R = H1D; C = H2D;
  } else {                       // W2: 4 x 4 x 2
    int bb = b - 256; s = bb / 8; int t = bb % 8; dt = t / 2; ht = t % 2;
    src = W2 + s * H2D * H3D; dst = W2T + s * H3D * H2D; R = H2D; C = H3D;
  }
  int tx = threadIdx.x & 31, ty = threadIdx.x >> 5;
#pragma unroll
  for (int k = 0; k < 4; ++k)
    tile[ty + 8 * k][tx] = src[(size_t)(dt * 32 + ty + 8 * k) * C + ht * 32 + tx];
  __syncthreads();
#pragma unroll
  for (int k = 0; k < 4; ++k)
    dst[(size_t)(ht * 32 + ty + 8 * k) * R + dt * 32 + tx] = f2bf(tile[tx][ty + 8 * k]);
}

// Block = 1 atom x 64 rows. Staging mapping: each wave-instruction reads
// 4 x 256B runs (vs 16 x 64B before) -> DRAM burst-friendly. Grid is
// atom-major so co-resident blocks cover a dense contiguous x footprint.
// H0/H1/H2 alias the x double-buffers -> 35 KB LDS -> 4 blocks/CU.
__global__ __launch_bounds__(256, 4) void mlp_fused(
    const float* __restrict__ x, const int* __restrict__ species,
    const unsigned short* __restrict__ W0T, const unsigned short* __restrict__ W1T,
    const unsigned short* __restrict__ W2T,
    const float* __restrict__ b0, const float* __restrict__ b1,
    const float* __restrict__ b2, const float* __restrict__ W3,
    const float* __restrict__ b3, float* __restrict__ out) {
  // 136-short row stride: 16B-aligned b128 reads, <=2-way bank aliasing (free).
  __shared__ __align__(16) unsigned short xbuf0[MT * 136];  // c0,c2; later H1
  __shared__ __align__(16) unsigned short xbuf1[MT * 136];  // c1;    later H0, then H2
  __shared__ float W3s[H3D];
  unsigned short* H0 = xbuf1;
  unsigned short* H1 = xbuf0;
  float* H2 = (float*)xbuf1;   // [64][68] fp32

  const int a = blockIdx.x;          // atom-major: dense device-wide x footprint
  const int brow0 = blockIdx.y * MT;
  const int sp = species[a];
  const int tid = threadIdx.x;
  const int wave = tid >> 6;
  const int lane = tid & 63;
  const int q = lane >> 4;   // A/B k-quad, C/D row-quad
  const int r = lane & 15;   // A row / B col / C col

  const float4v zero = {0.f, 0.f, 0.f, 0.f};

  // staging coords: thread (srow16, c16) covers rows srow16+16h (h=0..3),
  // two 16B pieces per row per 128-float chunk -> 256B contiguous per 16 lanes
  const int srow16 = tid >> 4;
  const int c16 = tid & 15;
  const float* xbase = x + ((size_t)(brow0 + srow16) * A_DIM + a) * D_DIM + c16 * 4;
  unsigned short* xd0 = xbuf0 + srow16 * 136 + c16 * 4;
  unsigned short* xd1 = xbuf1 + srow16 * 136 + c16 * 4;
  const unsigned short* w0base =
      W0T + (size_t)sp * H1D * D_DIM + (wave * 32 + r) * D_DIM + q * 8;

  // ---- prologue: chunk 0 loads -> convert -> xbuf0 ----
  float4v xv[8];
#pragma unroll
  for (int h = 0; h < 4; ++h) {
    xv[2 * h]     = *(const float4v*)(xbase + (size_t)h * 16 * XROW);
    xv[2 * h + 1] = *(const float4v*)(xbase + (size_t)h * 16 * XROW + 64);
  }
  if (tid < H3D) W3s[tid] = W3[sp * H3D + tid];
  short8 bf[4][2];
#pragma unroll
  for (int kk = 0; kk < 4; ++kk)
#pragma unroll
    for (int n = 0; n < 2; ++n)
      bf[kk][n] = *(const short8*)(w0base + n * 16 * D_DIM + kk * 32);
#pragma unroll
  for (int h = 0; h < 4; ++h) {
    store_bf4(xd0 + h * 16 * 136, xv[2 * h]);
    store_bf4(xd0 + h * 16 * 136 + 64, xv[2 * h + 1]);
  }
  __syncthreads();   // (b0) xbuf0 published

  float4v acc0[4][2];
#pragma unroll
  for (int g = 0; g < 4; ++g) { acc0[g][0] = zero; acc0[g][1] = zero; }

  // ---- chunk 0: MFMA on xbuf0; chunk-1 x loads in flight ----
#pragma unroll
  for (int h = 0; h < 4; ++h) {
    xv[2 * h]     = *(const float4v*)(xbase + (size_t)h * 16 * XROW + 128);
    xv[2 * h + 1] = *(const float4v*)(xbase + (size_t)h * 16 * XROW + 192);
  }
#pragma unroll
  for (int g = 0; g < 4; ++g)
#pragma unroll
    for (int kk = 0; kk < 4; ++kk) {
      short8 af = *(const short8*)(xbuf0 + (g * 16 + r) * 136 + kk * 32 + q * 8);
      acc0[g][0] = __builtin_amdgcn_mfma_f32_16x16x32_bf16(af, bf[kk][0], acc0[g][0], 0, 0, 0);
      acc0[g][1] = __builtin_amdgcn_mfma_f32_16x16x32_bf16(af, bf[kk][1], acc0[g][1], 0, 0, 0);
    }
#pragma unroll
  for (int h = 0; h < 4; ++h) {
    store_bf4(xd1 + h * 16 * 136, xv[2 * h]);
    store_bf4(xd1 + h * 16 * 136 + 64, xv[2 * h + 1]);
  }
  __syncthreads();   // (b1) xbuf1 published

  // ---- chunk 1: bf(c1) first, then chunk-2 x loads ----
#pragma unroll
  for (int kk = 0; kk < 4; ++kk)
#pragma unroll
    for (int n = 0; n < 2; ++n)
      bf[kk][n] = *(const short8*)(w0base + n * 16 * D_DIM + 128 + kk * 32);
#pragma unroll
  for (int h = 0; h < 4; ++h) {
    xv[2 * h]     = *(const float4v*)(xbase + (size_t)h * 16 * XROW + 256);
    xv[2 * h + 1] = *(const float4v*)(xbase + (size_t)h * 16 * XROW + 320);
  }
#pragma unroll
  for (int g = 0; g < 4; ++g)
#pragma unroll
    for (int kk = 0; kk < 4; ++kk) {
      short8 af = *(const short8*)(xbuf1 + (g * 16 + r) * 136 + kk * 32 + q * 8);
      acc0[g][0] = __builtin_amdgcn_mfma_f32_16x16x32_bf16(af, bf[kk][0], acc0[g][0], 0, 0, 0);
      acc0[g][1] = __builtin_amdgcn_mfma_f32_16x16x32_bf16(af, bf[kk][1], acc0[g][1], 0, 0, 0);
    }
#pragma unroll
  for (int h = 0; h < 4; ++h) {
    store_bf4(xd0 + h * 16 * 136, xv[2 * h]);
    store_bf4(xd0 + h * 16 * 136 + 64, xv[2 * h + 1]);
  }
  __syncthreads();   // (b2) xbuf0 re-published (chunk 2)

  // ---- chunk 2: MFMA on xbuf0 ----
#pragma unroll
  for (int kk = 0; kk < 4; ++kk)
#pragma unroll
    for (int n = 0; n < 2; ++n)
      bf[kk][n] = *(const short8*)(w0base + n * 16 * D_DIM + 256 + kk * 32);
#pragma unroll
  for (int g = 0; g < 4; ++g)
#pragma unroll
    for (int kk = 0; kk < 4; ++kk) {
      short8 af = *(const short8*)(xbuf0 + (g * 16 + r) * 136 + kk * 32 + q * 8);
      acc0[g][0] = __builtin_amdgcn_mfma_f32_16x16x32_bf16(af, bf[kk][0], acc0[g][0], 0, 0, 0);
      acc0[g][1] = __builtin_amdgcn_mfma_f32_16x16x32_bf16(af, bf[kk][1], acc0[g][1], 0, 0, 0);
    }
  // H0 (=xbuf1) writes: xbuf1's last reads drained at (b2); chunk-2 MFMA of
  // other waves touches only xbuf0 -> no barrier needed here.
  {
    const float* b0p = b0 + sp * H1D;
#pragma unroll
    for (int n = 0; n < 2; ++n) {
      float bias = b0p[wave * 32 + n * 16 + r];
#pragma unroll
      for (int g = 0; g < 4; ++g)
#pragma unroll
        for (int i = 0; i < 4; ++i) {
          float y = acc0[g][n][i] + bias;
          H0[(g * 16 + q * 4 + i) * 136 + wave * 32 + n * 16 + r] = f2bf(__expf(-y * y));
        }
    }
  }
  __syncthreads();   // (b3) H0 published; xbuf0 free

  // ---------------- layer 1: [64x128] @ [128x128]; H0 -> H1 (=xbuf0) ----------------
  {
    float4v acc1[4][2];
#pragma unroll
    for (int g = 0; g < 4; ++g) { acc1[g][0] = zero; acc1[g][1] = zero; }
    const unsigned short* w1base =
        W1T + (size_t)sp * H2D * H1D + (wave * 32 + r) * H1D + q * 8;
    short8 wf[4][2];
#pragma unroll
    for (int kk = 0; kk < 4; ++kk)
#pragma unroll
      for (int n = 0; n < 2; ++n)
        wf[kk][n] = *(const short8*)(w1base + n * 16 * H1D + kk * 32);
#pragma unroll
    for (int g = 0; g < 4; ++g)
#pragma unroll
      for (int kk = 0; kk < 4; ++kk) {
        short8 af = *(const short8*)(H0 + (g * 16 + r) * 136 + kk * 32 + q * 8);
        acc1[g][0] = __builtin_amdgcn_mfma_f32_16x16x32_bf16(af, wf[kk][0], acc1[g][0], 0, 0, 0);
        acc1[g][1] = __builtin_amdgcn_mfma_f32_16x16x32_bf16(af, wf[kk][1], acc1[g][1], 0, 0, 0);
      }
    const float* b1p = b1 + sp * H2D;
#pragma unroll
    for (int n = 0; n < 2; ++n) {
      float bias = b1p[wave * 32 + n * 16 + r];
#pragma unroll
      for (int g = 0; g < 4; ++g)
#pragma unroll
        for (int i = 0; i < 4; ++i) {
          float y = acc1[g][n][i] + bias;
          H1[(g * 16 + q * 4 + i) * 136 + wave * 32 + n * 16 + r] = f2bf(__expf(-y * y));
        }
    }
  }
  __syncthreads();   // (b4) H1 published; all H0 reads done

  // ---------------- layer 2: [64x128] @ [128x64]; H1 -> H2 (=xbuf1) ----------------
  {
    float4v acc2[4];
#pragma unroll
    for (int g = 0; g < 4; ++g) acc2[g] = zero;
    const unsigned short* w2base =
        W2T + (size_t)sp * H3D * H2D + (wave * 16 + r) * H2D + q * 8;
    short8 wf[4];
#pragma unroll
    for (int kk = 0; kk < 4; ++kk)
      wf[kk] = *(const short8*)(w2base + kk * 32);
#pragma unroll
    for (int g = 0; g < 4; ++g)
#pragma unroll
      for (int kk = 0; kk < 4; ++kk) {
        short8 af = *(const short8*)(H1 + (g * 16 + r) * 136 + kk * 32 + q * 8);
        acc2[g] = __builtin_amdgcn_mfma_f32_16x16x32_bf16(af, wf[kk], acc2[g], 0, 0, 0);
      }
    float bias = b2[sp * H3D + wave * 16 + r];
#pragma unroll
    for (int g = 0; g < 4; ++g)
#pragma unroll
      for (int i = 0; i < 4; ++i) {
        float y = acc2[g][i] + bias;
        H2[(g * 16 + q * 4 + i) * 68 + wave * 16 + r] = __expf(-y * y);
      }
  }
  __syncthreads();   // (b5) H2 published

  // ---------------- layer 3: dot with W3[64] + cross-atom atomic sum ----------------
  {
    const int row = tid >> 2;
    const int seg = tid & 3;
    const float4v* h2p = (const float4v*)(H2 + row * 68 + seg * 16);
    const float4v* w3p = (const float4v*)(W3s + seg * 16);
    float4v sv = zero;
#pragma unroll
    for (int jj = 0; jj < 4; ++jj) sv += h2p[jj] * w3p[jj];
    float s = sv[0] + sv[1] + sv[2] + sv[3];
    s += __shfl_xor(s, 1);
    s += __shfl_xor(s, 2);
    if (seg == 0) atomicAdd(&out[brow0 + row], s + b3[sp]);
  }
}

extern "C" void kernel_launch(void* const* d_in, const int* in_sizes, int n_in,
                              void* d_out, int out_size, void* d_ws, size_t ws_size,
                              hipStream_t stream) {
  const float* x       = (const float*)d_in[0];
  const int*   species = (const int*)d_in[1];
  const float* W0 = (const float*)d_in[2];
  const float* b0 = (const float*)d_in[3];
  const float* W1 = (const float*)d_in[4];
  const float* b1 = (const float*)d_in[5];
  const float* W2 = (const float*)d_in[6];
  const float* b2 = (const float*)d_in[7];
  const float* W3 = (const float*)d_in[8];
  const float* b3 = (const float*)d_in[9];
  float* out = (float*)d_out;

  unsigned short* W0T = (unsigned short*)d_ws;
  unsigned short* W1T = W0T + S_DIM * H1D * D_DIM;
  unsigned short* W2T = W1T + S_DIM * H2D * H1D;

  hipMemsetAsync(d_out, 0, out_size * sizeof(float), stream);
  prep_weights<<<dim3(288), dim3(256), 0, stream>>>(W0, W1, W2, W0T, W1T, W2T);
  mlp_fused<<<dim3(A_DIM, B_DIM / MT), dim3(256), 0, stream>>>(
      x, species, W0T, W1T, W2T, b0, b1, b2, W3, b3, out);
}